// Round 6
// baseline (1231.605 us; speedup 1.0000x reference)
//
#include <hip/hip_runtime.h>

// Problem constants (MultiHeadAttention_14508399526473)
// Inputs fp32 (per reference). Outputs fp32: [out (B,S,D) | attn (B,H,S,S)].
#define B_ 2
#define S_ 2048
#define D_ 1024
#define H_ 16
#define DH_ 64
#define EPS_ 1e-6f

typedef short bf16x8 __attribute__((ext_vector_type(8)));  // 8 bf16 (4 VGPRs)
typedef float f32x4  __attribute__((ext_vector_type(4)));  // MFMA accumulator

#define MFMA16 __builtin_amdgcn_mfma_f32_16x16x32_bf16

// --- bf16 split helpers (RNE). x = hi + lo captures ~16 mantissa bits. ---
__device__ __forceinline__ ushort f2bf(float x) {
    uint u = __float_as_uint(x);
    return (ushort)((u + 0x7fffu + ((u >> 16) & 1u)) >> 16);
}
__device__ __forceinline__ float bf2f(ushort h) {
    return __uint_as_float(((uint)h) << 16);
}
__device__ __forceinline__ void split_bf(float x, ushort& hi, ushort& lo) {
    hi = f2bf(x);
    lo = f2bf(x - bf2f(hi));   // x - hi exact in fp32 (nearby values)
}

// ---------------------------------------------------------------------------
// Weight prep: W[k][n] fp32 -> Wt_hi/Wt_lo[n][k] bf16 (k-contiguous), 4 mats.
// ---------------------------------------------------------------------------
__global__ __launch_bounds__(256) void prep_weights_kernel(
    const float* __restrict__ w0, const float* __restrict__ w1,
    const float* __restrict__ w2, const float* __restrict__ w3,
    ushort* __restrict__ Wth, ushort* __restrict__ Wtl)
{
    const int wi = blockIdx.z;
    const float* W = (wi == 0) ? w0 : (wi == 1) ? w1 : (wi == 2) ? w2 : w3;
    ushort* th = Wth + (size_t)wi * D_ * D_;
    ushort* tl = Wtl + (size_t)wi * D_ * D_;
    const int k0 = blockIdx.x * 32, n0 = blockIdx.y * 32;
    const int tid = threadIdx.x;
    __shared__ float t[32][33];
#pragma unroll
    for (int l = 0; l < 4; ++l) {
        int idx = tid + l * 256;
        int kk = idx >> 5, nn = idx & 31;
        t[kk][nn] = W[(size_t)(k0 + kk) * D_ + n0 + nn];
    }
    __syncthreads();
#pragma unroll
    for (int l = 0; l < 4; ++l) {
        int idx = tid + l * 256;
        int nn = idx >> 5, kk = idx & 31;
        ushort h, lo;
        split_bf(t[kk][nn], h, lo);
        th[(size_t)(n0 + nn) * D_ + k0 + kk] = h;
        tl[(size_t)(n0 + nn) * D_ + k0 + kk] = lo;
    }
}

// ---------------------------------------------------------------------------
// Split-bf16 MFMA GEMM body (QKV projections only).
// MODE 1: bf16 hi/lo out [M][N]. MODE 2: bf16 hi/lo out [b][h][dh][S].
// ---------------------------------------------------------------------------
template <int MODE>
__device__ __forceinline__ void gemm_mfma_body(
    const float* __restrict__ A, const ushort* __restrict__ Bh,
    const ushort* __restrict__ Bl, const float* __restrict__ bias,
    ushort* __restrict__ Ch, ushort* __restrict__ Cl,
    int M, int N, int K, int bx, int by)
{
    __shared__ ushort Ah[128][40];   // [m][k], pad 40 shorts (80 B rows)
    __shared__ ushort Al[128][40];

    const int tid = threadIdx.x;
    const int lane = tid & 63, w = tid >> 6;
    const int l15 = lane & 15, l4 = lane >> 4;
    const int row0 = by * 128, col0 = bx * 128;
    const int wm = (w >> 1) * 64, wn = (w & 1) * 64;

    const f32x4 zf = {0.f, 0.f, 0.f, 0.f};
    f32x4 acc[4][4];
#pragma unroll
    for (int i = 0; i < 4; ++i)
#pragma unroll
        for (int j = 0; j < 4; ++j) acc[i][j] = zf;

    for (int k0 = 0; k0 < K; k0 += 32) {
#pragma unroll
        for (int l = 0; l < 4; ++l) {
            int idx = tid + l * 256;            // 0..1023
            int r = idx >> 3, c4 = (idx & 7) * 4;
            const float4 a = *(const float4*)&A[(size_t)(row0 + r) * K + k0 + c4];
            ushort h0, h1, h2, h3, q0, q1, q2, q3;
            split_bf(a.x, h0, q0); split_bf(a.y, h1, q1);
            split_bf(a.z, h2, q2); split_bf(a.w, h3, q3);
            *(ushort4*)&Ah[r][c4] = make_ushort4(h0, h1, h2, h3);
            *(ushort4*)&Al[r][c4] = make_ushort4(q0, q1, q2, q3);
        }
        bf16x8 bh_[4], bl_[4];
#pragma unroll
        for (int j = 0; j < 4; ++j) {
            const size_t bo = (size_t)(col0 + wn + j * 16 + l15) * K + k0 + l4 * 8;
            bh_[j] = *(const bf16x8*)&Bh[bo];
            bl_[j] = *(const bf16x8*)&Bl[bo];
        }
        __syncthreads();
        bf16x8 ah_[4], al_[4];
#pragma unroll
        for (int i = 0; i < 4; ++i) {
            ah_[i] = *(const bf16x8*)&Ah[wm + i * 16 + l15][l4 * 8];
            al_[i] = *(const bf16x8*)&Al[wm + i * 16 + l15][l4 * 8];
        }
#pragma unroll
        for (int i = 0; i < 4; ++i)
#pragma unroll
            for (int j = 0; j < 4; ++j) {
                acc[i][j] = MFMA16(ah_[i], bh_[j], acc[i][j], 0, 0, 0);
                acc[i][j] = MFMA16(ah_[i], bl_[j], acc[i][j], 0, 0, 0);
                acc[i][j] = MFMA16(al_[i], bh_[j], acc[i][j], 0, 0, 0);
            }
        __syncthreads();
    }

    // Epilogue. D frag: col = l15, row = l4*4 + e.
#pragma unroll
    for (int i = 0; i < 4; ++i) {
#pragma unroll
        for (int j = 0; j < 4; ++j) {
            const int col = col0 + wn + j * 16 + l15;
            const float bb = bias[col];
            const int mbase = row0 + wm + i * 16 + l4 * 4;
            if (MODE == 1) {
#pragma unroll
                for (int e = 0; e < 4; ++e) {
                    const int m = mbase + e;
                    ushort h, lo;
                    split_bf(acc[i][j][e] + bb, h, lo);
                    Ch[(size_t)m * N + col] = h;
                    Cl[(size_t)m * N + col] = lo;
                }
            } else {
                // Vt: [b][h][dh][S]; 4 consecutive s -> one ushort4 store.
                const int bb_ = mbase / S_;
                const int s0 = mbase - bb_ * S_;
                const int hh = col >> 6, dh = col & 63;
                ushort hv[4], lv[4];
#pragma unroll
                for (int e = 0; e < 4; ++e)
                    split_bf(acc[i][j][e] + bb, hv[e], lv[e]);
                const size_t ofs =
                    (((size_t)bb_ * H_ + hh) * DH_ + dh) * S_ + s0;
                *(ushort4*)&Ch[ofs] = make_ushort4(hv[0], hv[1], hv[2], hv[3]);
                *(ushort4*)&Cl[ofs] = make_ushort4(lv[0], lv[1], lv[2], lv[3]);
            }
        }
    }
}

// Fused QKV projections: z=0 -> Q bf16, z=1 -> K bf16, z=2 -> V transposed.
__global__ __launch_bounds__(256) void gemm_qkv_mfma(
    const float* __restrict__ q, const float* __restrict__ k,
    const float* __restrict__ v,
    const ushort* __restrict__ Wth, const ushort* __restrict__ Wtl,
    const float* __restrict__ bq, const float* __restrict__ bk,
    const float* __restrict__ bv,
    ushort* __restrict__ Qh, ushort* __restrict__ Ql,
    ushort* __restrict__ Kh, ushort* __restrict__ Kl,
    ushort* __restrict__ Vth, ushort* __restrict__ Vtl)
{
    const int z = blockIdx.z;
    const size_t wofs = (size_t)z * D_ * D_;
    if (z == 0)
        gemm_mfma_body<1>(q, Wth, Wtl, bq, Qh, Ql,
                          B_ * S_, D_, D_, blockIdx.x, blockIdx.y);
    else if (z == 1)
        gemm_mfma_body<1>(k, Wth + wofs, Wtl + wofs, bk, Kh, Kl,
                          B_ * S_, D_, D_, blockIdx.x, blockIdx.y);
    else
        gemm_mfma_body<2>(v, Wth + wofs, Wtl + wofs, bv, Vth, Vtl,
                          B_ * S_, D_, D_, blockIdx.x, blockIdx.y);
}

// ---------------------------------------------------------------------------
// Flash forward: online-softmax attention, ctx (bf16 hi/lo) + per-row m/inv.
// Grid (bh, S/64), 256 threads; wave w owns q-rows [qt*64+w*16, +16).
// Per 32-key tile: 12 QK-MFMA -> online max/exp/sum (shfl within 16-lane
// groups) -> P split-bf16 via wave-private LDS bounce -> 12 PV-MFMA.
// ---------------------------------------------------------------------------
__global__ __launch_bounds__(256) void flash_kernel(
    const ushort* __restrict__ Qh, const ushort* __restrict__ Ql,
    const ushort* __restrict__ Kh, const ushort* __restrict__ Kl,
    const ushort* __restrict__ Vth, const ushort* __restrict__ Vtl,
    ushort* __restrict__ Ch, ushort* __restrict__ Cl,
    float* __restrict__ Mrow, float* __restrict__ Irow)
{
    __shared__ ushort Pbh[4][16][40];   // per-wave P bounce (transpose)
    __shared__ ushort Pbl[4][16][40];
    const int bh = blockIdx.x, qt = blockIdx.y;
    const int b = bh >> 4, h = bh & 15;
    const int tid = threadIdx.x;
    const int w = tid >> 6, lane = tid & 63;
    const int l15 = lane & 15, l4 = lane >> 4;
    const int q0 = qt * 64 + w * 16;

    // Q A-frags: row = l15, k = l4*8 (+32 for second half of D-head).
    const size_t qb = ((size_t)b * S_ + q0 + l15) * D_ + h * DH_ + l4 * 8;
    const bf16x8 ah0 = *(const bf16x8*)&Qh[qb];
    const bf16x8 ah1 = *(const bf16x8*)&Qh[qb + 32];
    const bf16x8 al0 = *(const bf16x8*)&Ql[qb];
    const bf16x8 al1 = *(const bf16x8*)&Ql[qb + 32];

    const size_t vbase = ((size_t)b * H_ + h) * (size_t)DH_ * S_;

    float m_run[4], l_run[4];
#pragma unroll
    for (int e = 0; e < 4; ++e) { m_run[e] = -INFINITY; l_run[e] = 0.f; }
    const f32x4 zf = {0.f, 0.f, 0.f, 0.f};
    f32x4 acc[4] = {zf, zf, zf, zf};    // rows l4*4+e, dh-cols j*16+l15

    const int kmax = q0 + 16;
    for (int kt = 0; kt < kmax; kt += 32) {
        // --- scores for 32 keys (2 col-frags), masked + scaled ---
        f32x4 s0, s1;
#pragma unroll
        for (int cf = 0; cf < 2; ++cf) {
            const int kc0 = kt + cf * 16;
            const size_t kb = ((size_t)b * S_ + kc0 + l15) * D_ + h * DH_ + l4 * 8;
            const bf16x8 kh0 = *(const bf16x8*)&Kh[kb];
            const bf16x8 kh1 = *(const bf16x8*)&Kh[kb + 32];
            const bf16x8 kl0 = *(const bf16x8*)&Kl[kb];
            const bf16x8 kl1 = *(const bf16x8*)&Kl[kb + 32];
            f32x4 a = zf;
            a = MFMA16(ah0, kh0, a, 0, 0, 0);
            a = MFMA16(ah0, kl0, a, 0, 0, 0);
            a = MFMA16(al0, kh0, a, 0, 0, 0);
            a = MFMA16(ah1, kh1, a, 0, 0, 0);
            a = MFMA16(ah1, kl1, a, 0, 0, 0);
            a = MFMA16(al1, kh1, a, 0, 0, 0);
            const int kk = kc0 + l15;
            f32x4 sv;
#pragma unroll
            for (int e = 0; e < 4; ++e) {
                const int qi = q0 + l4 * 4 + e;
                sv[e] = (kk <= qi) ? a[e] * 0.125f : -INFINITY;
            }
            if (cf == 0) s0 = sv; else s1 = sv;
        }
        // --- online softmax update (per row e; reduce over 16 l15 lanes) ---
        float p0[4], p1[4], f_[4];
#pragma unroll
        for (int e = 0; e < 4; ++e) {
            float mx = fmaxf(s0[e], s1[e]);
            mx = fmaxf(mx, __shfl_xor(mx, 1));
            mx = fmaxf(mx, __shfl_xor(mx, 2));
            mx = fmaxf(mx, __shfl_xor(mx, 4));
            mx = fmaxf(mx, __shfl_xor(mx, 8));
            const float mn = fmaxf(m_run[e], mx);
            f_[e] = __expf(m_run[e] - mn);
            m_run[e] = mn;
            p0[e] = __expf(s0[e] - mn);
            p1[e] = __expf(s1[e] - mn);
            float sm = p0[e] + p1[e];
            sm += __shfl_xor(sm, 1);
            sm += __shfl_xor(sm, 2);
            sm += __shfl_xor(sm, 4);
            sm += __shfl_xor(sm, 8);
            l_run[e] = l_run[e] * f_[e] + sm;
        }
#pragma unroll
        for (int j = 0; j < 4; ++j)
#pragma unroll
            for (int e = 0; e < 4; ++e) acc[j][e] *= f_[e];
        // --- P bounce: D-layout (row l4*4+e, col l15) -> A-frag, split ---
#pragma unroll
        for (int e = 0; e < 4; ++e) {
            ushort hh, ll;
            split_bf(p0[e], hh, ll);
            Pbh[w][l4 * 4 + e][l15] = hh;
            Pbl[w][l4 * 4 + e][l15] = ll;
            split_bf(p1[e], hh, ll);
            Pbh[w][l4 * 4 + e][16 + l15] = hh;
            Pbl[w][l4 * 4 + e][16 + l15] = ll;
        }
        // wave-private LDS: same-wave RAW ordered by compiler lgkmcnt.
        const bf16x8 pah = *(const bf16x8*)&Pbh[w][l15][l4 * 8];
        const bf16x8 pal = *(const bf16x8*)&Pbl[w][l15][l4 * 8];
        // --- PV ---
#pragma unroll
        for (int j = 0; j < 4; ++j) {
            const size_t vo = vbase + (size_t)(j * 16 + l15) * S_ + kt + l4 * 8;
            const bf16x8 vh = *(const bf16x8*)&Vth[vo];
            const bf16x8 vl = *(const bf16x8*)&Vtl[vo];
            acc[j] = MFMA16(pah, vh, acc[j], 0, 0, 0);
            acc[j] = MFMA16(pah, vl, acc[j], 0, 0, 0);
            acc[j] = MFMA16(pal, vh, acc[j], 0, 0, 0);
        }
    }
    // --- epilogue: ctx bf16 hi/lo, plus m/inv per row ---
    float inv[4];
#pragma unroll
    for (int e = 0; e < 4; ++e) inv[e] = 1.f / l_run[e];
#pragma unroll
    for (int j = 0; j < 4; ++j)
#pragma unroll
        for (int e = 0; e < 4; ++e) {
            const size_t mo = ((size_t)b * S_ + q0 + l4 * 4 + e) * D_
                              + h * DH_ + j * 16 + l15;
            ushort hh, ll;
            split_bf(acc[j][e] * inv[e], hh, ll);
            Ch[mo] = hh; Cl[mo] = ll;
        }
    if (l15 == 0) {
#pragma unroll
        for (int e = 0; e < 4; ++e) {
            Mrow[(size_t)bh * S_ + q0 + l4 * 4 + e] = m_run[e];
            Irow[(size_t)bh * S_ + q0 + l4 * 4 + e] = inv[e];
        }
    }
}

// ---------------------------------------------------------------------------
// attn writer: recompute QK per 128x128 tile (LDS-free), apply
// exp(s*0.125 - m[q]) * inv[q]; strictly-upper tiles stream zeros.
// Grid (S/128, S/128, B*H), 256 threads, 4 waves (64x64 quadrants).
// ---------------------------------------------------------------------------
__global__ __launch_bounds__(256) void attn_write_kernel(
    const ushort* __restrict__ Qh, const ushort* __restrict__ Ql,
    const ushort* __restrict__ Kh, const ushort* __restrict__ Kl,
    const float* __restrict__ Mrow, const float* __restrict__ Irow,
    float* __restrict__ attn)
{
    const int tk = blockIdx.x, tq = blockIdx.y, bh = blockIdx.z;
    const int tid = threadIdx.x;
    if (tk > tq) {                       // upper triangle: exact zeros
        const float4 z = {0.f, 0.f, 0.f, 0.f};
        for (int idx = tid; idx < 128 * 32; idx += 256) {
            const int r = idx >> 5, c = idx & 31;
            *(float4*)&attn[((size_t)bh * S_ + tq * 128 + r) * S_
                            + tk * 128 + c * 4] = z;
        }
        return;
    }
    const int b = bh >> 4, h = bh & 15;
    const int lane = tid & 63, w = tid >> 6;
    const int l15 = lane & 15, l4 = lane >> 4;
    const int wm = (w >> 1) * 64, wn = (w & 1) * 64;

    const size_t qbase = ((size_t)b * S_ + tq * 128 + wm) * D_ + h * DH_;
    const size_t kbase = ((size_t)b * S_ + tk * 128 + wn) * D_ + h * DH_;

    const f32x4 zf = {0.f, 0.f, 0.f, 0.f};
    f32x4 acc[4][4];
#pragma unroll
    for (int i = 0; i < 4; ++i)
#pragma unroll
        for (int j = 0; j < 4; ++j) acc[i][j] = zf;

#pragma unroll
    for (int ks = 0; ks < 2; ++ks) {
        const int ko = ks * 32 + l4 * 8;
        bf16x8 qh_[4], ql_[4], kh_[4], kl_[4];
#pragma unroll
        for (int i = 0; i < 4; ++i) {
            const size_t qo = qbase + (size_t)(i * 16 + l15) * D_ + ko;
            qh_[i] = *(const bf16x8*)&Qh[qo];
            ql_[i] = *(const bf16x8*)&Ql[qo];
            const size_t kko = kbase + (size_t)(i * 16 + l15) * D_ + ko;
            kh_[i] = *(const bf16x8*)&Kh[kko];
            kl_[i] = *(const bf16x8*)&Kl[kko];
        }
#pragma unroll
        for (int i = 0; i < 4; ++i)
#pragma unroll
            for (int j = 0; j < 4; ++j) {
                acc[i][j] = MFMA16(qh_[i], kh_[j], acc[i][j], 0, 0, 0);
                acc[i][j] = MFMA16(qh_[i], kl_[j], acc[i][j], 0, 0, 0);
                acc[i][j] = MFMA16(ql_[i], kh_[j], acc[i][j], 0, 0, 0);
            }
    }

#pragma unroll
    for (int i = 0; i < 4; ++i) {
        float mi[4], ii[4];
        int qi_[4];
#pragma unroll
        for (int e = 0; e < 4; ++e) {
            qi_[e] = tq * 128 + wm + i * 16 + l4 * 4 + e;
            mi[e] = Mrow[(size_t)bh * S_ + qi_[e]];
            ii[e] = Irow[(size_t)bh * S_ + qi_[e]];
        }
#pragma unroll
        for (int j = 0; j < 4; ++j) {
            const int kk = tk * 128 + wn + j * 16 + l15;
#pragma unroll
            for (int e = 0; e < 4; ++e) {
                const float val = (kk <= qi_[e])
                    ? __expf(acc[i][j][e] * 0.125f - mi[e]) * ii[e] : 0.f;
                attn[((size_t)bh * S_ + qi_[e]) * S_ + kk] = val;
            }
        }
    }
}

// ---------------------------------------------------------------------------
// Output projection, LDS-free: pre = ctx(bf16 hi/lo) @ wo + bias + query.
// Grid (D/128, M/128), 256 threads, 4 waves (64x64 quadrants), K=1024.
// ---------------------------------------------------------------------------
__global__ __launch_bounds__(256) void gemm_out2_kernel(
    const ushort* __restrict__ Ah, const ushort* __restrict__ Al,
    const ushort* __restrict__ Bh, const ushort* __restrict__ Bl,
    const float* __restrict__ bias, const float* __restrict__ residual,
    float* __restrict__ out)
{
    const int tid = threadIdx.x;
    const int lane = tid & 63, w = tid >> 6;
    const int l15 = lane & 15, l4 = lane >> 4;
    const int row0 = blockIdx.y * 128, col0 = blockIdx.x * 128;
    const int wm = (w >> 1) * 64, wn = (w & 1) * 64;

    const f32x4 zf = {0.f, 0.f, 0.f, 0.f};
    f32x4 acc[4][4];
#pragma unroll
    for (int i = 0; i < 4; ++i)
#pragma unroll
        for (int j = 0; j < 4; ++j) acc[i][j] = zf;

    for (int k0 = 0; k0 < D_; k0 += 32) {
        bf16x8 ah_[4], al_[4], bh_[4], bl_[4];
#pragma unroll
        for (int i = 0; i < 4; ++i) {
            const size_t ao = (size_t)(row0 + wm + i * 16 + l15) * D_ + k0 + l4 * 8;
            ah_[i] = *(const bf16x8*)&Ah[ao];
            al_[i] = *(const bf16x8*)&Al[ao];
            const size_t bo = (size_t)(col0 + wn + i * 16 + l15) * D_ + k0 + l4 * 8;
            bh_[i] = *(const bf16x8*)&Bh[bo];
            bl_[i] = *(const bf16x8*)&Bl[bo];
        }
#pragma unroll
        for (int i = 0; i < 4; ++i)
#pragma unroll
            for (int j = 0; j < 4; ++j) {
                acc[i][j] = MFMA16(ah_[i], bh_[j], acc[i][j], 0, 0, 0);
                acc[i][j] = MFMA16(ah_[i], bl_[j], acc[i][j], 0, 0, 0);
                acc[i][j] = MFMA16(al_[i], bh_[j], acc[i][j], 0, 0, 0);
            }
    }

#pragma unroll
    for (int i = 0; i < 4; ++i)
#pragma unroll
        for (int j = 0; j < 4; ++j) {
            const int col = col0 + wn + j * 16 + l15;
            const float bb = bias[col];
#pragma unroll
            for (int e = 0; e < 4; ++e) {
                const int m = row0 + wm + i * 16 + l4 * 4 + e;
                out[(size_t)m * D_ + col] =
                    acc[i][j][e] + bb + residual[(size_t)m * D_ + col];
            }
        }
}

// ---------------------------------------------------------------------------
// Row LayerNorm: one block per row of [B*S, D], fp32 in, fp32 out. (verified)
// ---------------------------------------------------------------------------
__global__ __launch_bounds__(256) void ln_kernel(
    const float* __restrict__ X, const float* __restrict__ gamma,
    const float* __restrict__ beta, float* __restrict__ out)
{
    const int row = blockIdx.x;
    const int tid = threadIdx.x;
    const float* x = X + (size_t)row * D_;
    __shared__ float red[256];

    float s = 0.f;
    for (int i = tid; i < D_; i += 256) s += x[i];
    red[tid] = s;
    __syncthreads();
    for (int t = 128; t > 0; t >>= 1) {
        if (tid < t) red[tid] += red[tid + t];
        __syncthreads();
    }
    const float mu = red[0] * (1.f / D_);
    __syncthreads();

    float v = 0.f;
    for (int i = tid; i < D_; i += 256) {
        float t = x[i] - mu;
        v += t * t;
    }
    red[tid] = v;
    __syncthreads();
    for (int t = 128; t > 0; t >>= 1) {
        if (tid < t) red[tid] += red[tid + t];
        __syncthreads();
    }
    const float r = rsqrtf(red[0] * (1.f / D_) + EPS_);

    for (int i = tid; i < D_; i += 256) {
        float o = (x[i] - mu) * r * gamma[i] + beta[i];
        out[(size_t)row * D_ + i] = o;
    }
}

// ---------------------------------------------------------------------------
extern "C" void kernel_launch(void* const* d_in, const int* in_sizes, int n_in,
                              void* d_out, int out_size, void* d_ws, size_t ws_size,
                              hipStream_t stream)
{
    const float* query = (const float*)d_in[0];
    const float* key   = (const float*)d_in[1];
    const float* value = (const float*)d_in[2];
    // d_in[3] = mask (causal) — applied structurally (lower-tri + zero tail)
    const float* wq_w = (const float*)d_in[4];
    const float* wq_b = (const float*)d_in[5];
    const float* wk_w = (const float*)d_in[6];
    const float* wk_b = (const float*)d_in[7];
    const float* wv_w = (const float*)d_in[8];
    const float* wv_b = (const float*)d_in[9];
    const float* wo_w = (const float*)d_in[10];
    const float* wo_b = (const float*)d_in[11];
    const float* ln_g = (const float*)d_in[12];
    const float* ln_b = (const float*)d_in[13];

    float* out_f  = (float*)d_out;                        // (B,S,D)
    float* attn_f = out_f + (size_t)B_ * S_ * D_;         // (B,H,S,S)

    // Workspace carve-up (96 MB total, unchanged footprint).
    const size_t NELEM = (size_t)B_ * S_ * D_;            // 4 Mi elements
    const size_t WELEM = (size_t)4 * D_ * D_;             // 4 weight mats
    char* p = (char*)d_ws;
    ushort* Wth  = (ushort*)p; p += WELEM * 2;            // 8 MB
    ushort* Wtl  = (ushort*)p; p += WELEM * 2;            // 8 MB
    ushort* Qh   = (ushort*)p; p += NELEM * 2;            // 8 MB
    ushort* Ql   = (ushort*)p; p += NELEM * 2;
    ushort* Kh   = (ushort*)p; p += NELEM * 2;
    ushort* Kl   = (ushort*)p; p += NELEM * 2;
    ushort* Vth  = (ushort*)p; p += NELEM * 2;            // [b][h][dh][S]
    ushort* Vtl  = (ushort*)p; p += NELEM * 2;
    ushort* Ctxh = (ushort*)p; p += NELEM * 2;            // ctx bf16 hi
    ushort* Ctxl = (ushort*)p; p += NELEM * 2;            // ctx bf16 lo
    float*  pre  = (float*)p;  p += NELEM * 4;            // 16 MB
    // m/inv (256 KB each) alias the head of `pre`: read by attn_write BEFORE
    // gemm_out2 overwrites pre (stream-ordered).
    float* Mrow = pre;                                    // [B*H][S]
    float* Irow = pre + (size_t)B_ * H_ * S_;

    // 1) Transpose + split weights -> Wt[n][k] bf16 hi/lo.
    hipLaunchKernelGGL(prep_weights_kernel, dim3(D_ / 32, D_ / 32, 4), dim3(256),
                       0, stream, wq_w, wk_w, wv_w, wo_w, Wth, Wtl);

    // 2) Fused QKV projections (MFMA): Q/K bf16 hi/lo, V transposed per head.
    hipLaunchKernelGGL(gemm_qkv_mfma, dim3(D_ / 128, (B_ * S_) / 128, 3),
                       dim3(256), 0, stream,
                       query, key, value, Wth, Wtl, wq_b, wk_b, wv_b,
                       Qh, Ql, Kh, Kl, Vth, Vtl);

    // 3) Flash forward: ctx (bf16 hi/lo) + per-row m/inv. High occupancy,
    //    uniform blocks, 10 KB LDS.
    hipLaunchKernelGGL(flash_kernel, dim3(B_ * H_, S_ / 64), dim3(256),
                       0, stream, Qh, Ql, Kh, Kl, Vth, Vtl,
                       Ctxh, Ctxl, Mrow, Irow);

    // 4) attn writer: recompute QK per tile, exp(s-m)*inv, zeros above diag.
    hipLaunchKernelGGL(attn_write_kernel, dim3(S_ / 128, S_ / 128, B_ * H_),
                       dim3(256), 0, stream,
                       Qh, Ql, Kh, Kl, Mrow, Irow, attn_f);

    // 5) Output projection (LDS-free, ctx pre-split) + residual, then LN.
    hipLaunchKernelGGL(gemm_out2_kernel, dim3(D_ / 128, (B_ * S_) / 128),
                       dim3(256), 0, stream,
                       Ctxh, Ctxl, Wth + (size_t)3 * D_ * D_,
                       Wtl + (size_t)3 * D_ * D_, wo_b, query, pre);

    hipLaunchKernelGGL(ln_kernel, dim3(B_ * S_), dim3(256), 0, stream,
                       pre, ln_g, ln_b, out_f);
}